// Round 1
// baseline (8101.138 us; speedup 1.0000x reference)
//
#include <hip/hip_runtime.h>
#include <stdint.h>

#define B_   512
#define T_   512

typedef __attribute__((ext_vector_type(8))) __bf16 bf16x8;
typedef __attribute__((ext_vector_type(4))) float f32x4;
typedef __attribute__((ext_vector_type(8))) unsigned short u16x8;

// Layer geometry:
//   l : S (out) | C (cat=in) | NP (pad16) | NPT | KT (=ceil(C/32)) | KP | XOFF | RS (=KP+8)
//   0 : 231     | 232        | 240        | 15  | 8                | 256| 1    | 264
//   1 : 153     | 384        | 160        | 10  | 12               | 384| 231  | 392
//   2 : 128     | 281        | 128        | 8   | 9                | 288| 153  | 296
// Packed weights (bf16) in d_ws: per layer, 3 matrices (G1=W1*mask, G2=W2*mask, G3=Wa+Wb),
// fragment order: chunk c = ((m*NPT + nt)*KT + kt)*64 + lane, 8 bf16 per chunk:
//   elem i = G[nt*16 + (lane&15)][kt*32 + (lane>>4)*8 + i]  (zero outside S x C)
// Layer elem offsets in ws (uint16 units): L0=0, L1=184320, L2=368640; total 479232 elems.

__device__ __forceinline__ uint16_t f2bf(float f){
  union { float f; uint32_t u; } v; v.f = f;
  uint32_t u = v.u;
  u += 0x7FFFu + ((u >> 16) & 1u);
  return (uint16_t)(u >> 16);
}
__device__ __forceinline__ float bf2f(uint16_t h){
  union { uint32_t u; float f; } v; v.u = ((uint32_t)h) << 16;
  return v.f;
}
__device__ __forceinline__ float sigm_f(float x){
  return __builtin_amdgcn_rcpf(1.0f + __builtin_amdgcn_exp2f(-1.4426950408889634f * x));
}
__device__ __forceinline__ float tanh_f(float x){
  // tanh(x) = 2*sigmoid(2x) - 1
  return 2.0f * __builtin_amdgcn_rcpf(1.0f + __builtin_amdgcn_exp2f(-2.8853900817779268f * x)) - 1.0f;
}

__global__ void pack_w(const float* __restrict__ W1, const float* __restrict__ W2,
                       const float* __restrict__ Wa, const float* __restrict__ Wb,
                       const float* __restrict__ Msk, uint16_t* __restrict__ dst,
                       int NPT, int KT, int S, int C)
{
  int c = blockIdx.x * 256 + threadIdx.x;
  int chunks = 3 * NPT * KT * 64;
  if (c >= chunks) return;
  int perN = KT * 64;
  int n3 = c / perN, r = c % perN;
  int kt = r >> 6, lane = r & 63;
  int m = n3 / NPT, nt = n3 % NPT;
  int j = nt * 16 + (lane & 15);
  int kb = kt * 32 + (lane >> 4) * 8;
  u16x8 o;
  #pragma unroll
  for (int i = 0; i < 8; ++i){
    int k = kb + i;
    float v = 0.f;
    if (j < S && k < C){
      size_t idx = (size_t)j * C + k;
      if (m == 0)      v = W1[idx] * Msk[idx];
      else if (m == 1) v = W2[idx] * Msk[idx];
      else             v = Wa[idx] + Wb[idx];
    }
    o[i] = f2bf(v);
  }
  *(u16x8*)(dst + (size_t)c * 8) = o;
}

template<int LNUM, int S, int NPT, int KT, int XOFF, int RSC, int RSN>
__device__ __forceinline__ void layer_step(
    uint16_t* Xc, uint16_t* Xn, const float* BiasL, const uint16_t* __restrict__ Wl,
    float* __restrict__ outp, int t, int b0, int wave, int lane)
{
  const int llo = lane & 15, lhi = lane >> 4;
  constexpr int NP = NPT * 16;
  constexpr int NJ = (NPT + 7) >> 3;   // jt tiles per wave (8 waves)
  f32x4 acc[NJ][3];
  #pragma unroll
  for (int ji = 0; ji < NJ; ++ji){
    const int jt = wave + ji * 8;
    f32x4 z = {0.f, 0.f, 0.f, 0.f};
    acc[ji][0] = z; acc[ji][1] = z; acc[ji][2] = z;
    if (jt < NPT){
      const bf16x8* w0 = (const bf16x8*)(Wl + ((size_t)((0 * NPT + jt) * KT) * 64 + lane) * 8);
      const bf16x8* w1 = (const bf16x8*)(Wl + ((size_t)((1 * NPT + jt) * KT) * 64 + lane) * 8);
      const bf16x8* w2 = (const bf16x8*)(Wl + ((size_t)((2 * NPT + jt) * KT) * 64 + lane) * 8);
      const uint16_t* arow = Xc + llo * RSC + lhi * 8;
      #pragma unroll 4
      for (int kt = 0; kt < KT; ++kt){
        bf16x8 a = *(const bf16x8*)(arow + kt * 32);
        acc[ji][0] = __builtin_amdgcn_mfma_f32_16x16x32_bf16(a, w0[kt * 64], acc[ji][0], 0, 0, 0);
        acc[ji][1] = __builtin_amdgcn_mfma_f32_16x16x32_bf16(a, w1[kt * 64], acc[ji][1], 0, 0, 0);
        acc[ji][2] = __builtin_amdgcn_mfma_f32_16x16x32_bf16(a, w2[kt * 64], acc[ji][2], 0, 0, 0);
      }
    }
  }
  __syncthreads();   // all waves done reading Xc before h-region overwrite
  #pragma unroll
  for (int ji = 0; ji < NJ; ++ji){
    const int jt = wave + ji * 8;
    if (jt < NPT){
      const int j = jt * 16 + llo;
      const float B1 = BiasL[0 * NP + j];
      const float B2 = BiasL[1 * NP + j];
      const float B3 = BiasL[2 * NP + j];
      const bool valid = (j < S);
      #pragma unroll
      for (int r = 0; r < 4; ++r){
        const int row = lhi * 4 + r;
        float ff1 = tanh_f(acc[ji][0][r] + B1);
        float ff2 = tanh_f(acc[ji][1][r] + B2);
        float tt  = sigm_f(acc[ji][2][r] + B3);
        float h = ff1 + tt * (ff2 - ff1);
        if (valid){
          uint16_t hb = f2bf(h);
          Xc[row * RSC + XOFF + j] = hb;          // own h for next step
          if constexpr (LNUM < 2)
            Xn[row * RSN + j] = hb;               // input region of next layer
          else
            outp[((size_t)(b0 + row) * T_ + t) * 128 + j] = h;  // rnn_out
        }
      }
    }
  }
  __syncthreads();
}

__global__ __launch_bounds__(512) void cfc_main(
    const float* __restrict__ elapsed, const float* __restrict__ enc,
    const float* __restrict__ b1_0, const float* __restrict__ b2_0,
    const float* __restrict__ ba0,  const float* __restrict__ bb0,
    const float* __restrict__ b1_1, const float* __restrict__ b2_1,
    const float* __restrict__ ba1,  const float* __restrict__ bb1,
    const float* __restrict__ b1_2, const float* __restrict__ b2_2,
    const float* __restrict__ ba2,  const float* __restrict__ bb2,
    const uint16_t* __restrict__ Wp, float* __restrict__ out)
{
  const int tid = threadIdx.x;
  const int wave = tid >> 6, lane = tid & 63;
  const int b0 = blockIdx.x * 16;

  __shared__ uint16_t X0[16 * 264];
  __shared__ uint16_t X1[16 * 392];
  __shared__ uint16_t X2[16 * 296];
  __shared__ float Bias0[3 * 240];
  __shared__ float Bias1[3 * 160];
  __shared__ float Bias2[3 * 128];

  // zero-init X (padding must be zero, forever)
  for (int i = tid; i < 16 * 264; i += 512) X0[i] = 0;
  for (int i = tid; i < 16 * 392; i += 512) X1[i] = 0;
  for (int i = tid; i < 16 * 296; i += 512) X2[i] = 0;
  __syncthreads();

  // initial hidden states from encoder_hidden
  for (int i = tid; i < 16 * 512; i += 512){
    int row = i >> 9, c = i & 511;
    float v = enc[(size_t)(b0 + row) * 512 + c];
    uint16_t hb = f2bf(v);
    if (c < 231)       X0[row * 264 + 1 + c] = hb;   // h0 at cols 1..231
    else if (c < 384)  X1[row * 392 + c] = hb;       // h1 at cols 231..383
    else               X2[row * 296 + (c - 231)] = hb; // h2 at cols 153..280
  }
  // biases (G3 bias = ba + bb), zero-padded
  for (int i = tid; i < 240; i += 512){
    Bias0[0 * 240 + i] = (i < 231) ? b1_0[i] : 0.f;
    Bias0[1 * 240 + i] = (i < 231) ? b2_0[i] : 0.f;
    Bias0[2 * 240 + i] = (i < 231) ? (ba0[i] + bb0[i]) : 0.f;
  }
  for (int i = tid; i < 160; i += 512){
    Bias1[0 * 160 + i] = (i < 153) ? b1_1[i] : 0.f;
    Bias1[1 * 160 + i] = (i < 153) ? b2_1[i] : 0.f;
    Bias1[2 * 160 + i] = (i < 153) ? (ba1[i] + bb1[i]) : 0.f;
  }
  for (int i = tid; i < 128; i += 512){
    Bias2[0 * 128 + i] = b1_2[i];
    Bias2[1 * 128 + i] = b2_2[i];
    Bias2[2 * 128 + i] = ba2[i] + bb2[i];
  }

  float xt = 0.f;
  if (tid < 16) xt = elapsed[(size_t)(b0 + tid) * T_];
  __syncthreads();

  for (int t = 0; t < T_; ++t){
    if (tid < 16){
      X0[tid * 264 + 0] = f2bf(xt);                       // x_t scalar column
      if (t + 1 < T_) xt = elapsed[(size_t)(b0 + tid) * T_ + t + 1]; // prefetch
    }
    __syncthreads();
    layer_step<0, 231, 15,  8,   1, 264, 392>(X0, X1, Bias0, Wp,          out, t, b0, wave, lane);
    layer_step<1, 153, 10, 12, 231, 392, 296>(X1, X2, Bias1, Wp + 184320, out, t, b0, wave, lane);
    layer_step<2, 128,  8,  9, 153, 296, 296>(X2, X2, Bias2, Wp + 368640, out, t, b0, wave, lane);
  }

  // rnn_hidden = concat(h0, h1, h2) at offset B*T*128
  const size_t OH = (size_t)B_ * T_ * 128;
  for (int i = tid; i < 16 * 512; i += 512){
    int row = i >> 9, c = i & 511;
    float v;
    if (c < 231)      v = bf2f(X0[row * 264 + 1 + c]);
    else if (c < 384) v = bf2f(X1[row * 392 + c]);
    else              v = bf2f(X2[row * 296 + (c - 231)]);
    out[OH + (size_t)(b0 + row) * 512 + c] = v;
  }
}

extern "C" void kernel_launch(void* const* d_in, const int* in_sizes, int n_in,
                              void* d_out, int out_size, void* d_ws, size_t ws_size,
                              hipStream_t stream)
{
  const float* elapsed = (const float*)d_in[0];
  const float* enc     = (const float*)d_in[1];
  // per layer l (base = 2 + 9*l): W1, b1, W2, b2, Wa, ba, Wb, bb, mask
  const float* W1_0 = (const float*)d_in[2];  const float* b1_0 = (const float*)d_in[3];
  const float* W2_0 = (const float*)d_in[4];  const float* b2_0 = (const float*)d_in[5];
  const float* Wa0  = (const float*)d_in[6];  const float* ba0  = (const float*)d_in[7];
  const float* Wb0  = (const float*)d_in[8];  const float* bb0  = (const float*)d_in[9];
  const float* M0   = (const float*)d_in[10];
  const float* W1_1 = (const float*)d_in[11]; const float* b1_1 = (const float*)d_in[12];
  const float* W2_1 = (const float*)d_in[13]; const float* b2_1 = (const float*)d_in[14];
  const float* Wa1  = (const float*)d_in[15]; const float* ba1  = (const float*)d_in[16];
  const float* Wb1  = (const float*)d_in[17]; const float* bb1  = (const float*)d_in[18];
  const float* M1   = (const float*)d_in[19];
  const float* W1_2 = (const float*)d_in[20]; const float* b1_2 = (const float*)d_in[21];
  const float* W2_2 = (const float*)d_in[22]; const float* b2_2 = (const float*)d_in[23];
  const float* Wa2  = (const float*)d_in[24]; const float* ba2  = (const float*)d_in[25];
  const float* Wb2  = (const float*)d_in[26]; const float* bb2  = (const float*)d_in[27];
  const float* M2   = (const float*)d_in[28];

  uint16_t* wp = (uint16_t*)d_ws;   // packed bf16 weights, 958464 bytes

  pack_w<<<90, 256, 0, stream>>>(W1_0, W2_0, Wa0, Wb0, M0, wp,          15,  8, 231, 232);
  pack_w<<<90, 256, 0, stream>>>(W1_1, W2_1, Wa1, Wb1, M1, wp + 184320, 10, 12, 153, 384);
  pack_w<<<54, 256, 0, stream>>>(W1_2, W2_2, Wa2, Wb2, M2, wp + 368640,  8,  9, 128, 281);

  cfc_main<<<32, 512, 0, stream>>>(elapsed, enc,
                                   b1_0, b2_0, ba0, bb0,
                                   b1_1, b2_1, ba1, bb1,
                                   b1_2, b2_2, ba2, bb2,
                                   wp, (float*)d_out);
}